// Round 6
// baseline (259.806 us; speedup 1.0000x reference)
//
#include <hip/hip_runtime.h>
#include <hip/hip_bf16.h>
#include <stdint.h>

// GCN 2-layer + linear head. fp32 accumulate, bf16 intermediate node tables.
// CSR build = two-level bucket counting sort (no scattered global atomics).
// GEMMs: M=2 register blocking + 16-col blocks -> ds_read amortized over 2 rows.

#define THREADS 256
#define NBUCK_MAX 1024
#define SORT_BLOCKS 200
#define CAP 4096

__device__ __forceinline__ unsigned int pack_bf2(float a, float b) {
    unsigned int ua = __float_as_uint(a);
    unsigned int ub = __float_as_uint(b);
    ua = (ua + 0x7FFFu + ((ua >> 16) & 1u)) >> 16;
    ub = (ub + 0x7FFFu + ((ub >> 16) & 1u)) >> 16;
    return ua | (ub << 16);
}
__device__ __forceinline__ float bf_lo(unsigned int u) { return __uint_as_float(u << 16); }
__device__ __forceinline__ float bf_hi(unsigned int u) { return __uint_as_float(u & 0xFFFF0000u); }

__global__ void k_detect_dtype(const unsigned int* ei_words, int* flag) {
    int is64 = 1;
    for (int i = 1; i < 64; i += 2) {
        if (ei_words[i] != 0u) { is64 = 0; break; }
    }
    *flag = is64;
}

__global__ void k_zero_int(int* p, int n) {
    int i = blockIdx.x * blockDim.x + threadIdx.x;
    if (i < n) p[i] = 0;
}

__global__ void k_bucket_hist(const void* ei, const int* flag, int* bucket_count, int E, int B) {
    __shared__ int h[NBUCK_MAX];
    int t = threadIdx.x;
    for (int i = t; i < B; i += THREADS) h[i] = 0;
    __syncthreads();
    int chunk = (E + gridDim.x - 1) / gridDim.x;
    int lo = blockIdx.x * chunk;
    int hi = min(lo + chunk, E);
    bool is64 = (*flag != 0);
    const long long* p64 = (const long long*)ei;
    const int* p32 = (const int*)ei;
    for (int e = lo + t; e < hi; e += THREADS) {
        int d = is64 ? (int)p64[(size_t)E + e] : p32[E + e];
        atomicAdd(&h[d >> 7], 1);
    }
    __syncthreads();
    for (int i = t; i < B; i += THREADS) {
        int c = h[i];
        if (c) atomicAdd(&bucket_count[i], c);
    }
}

__global__ void k_bucket_scan(const int* bucket_count, int* bucket_base, int* bucket_cursor, int B) {
    __shared__ int s[1024];
    int t = threadIdx.x;
    int c = (t < B) ? bucket_count[t] : 0;
    s[t] = c;
    __syncthreads();
    for (int off = 1; off < 1024; off <<= 1) {
        int v = (t >= off) ? s[t - off] : 0;
        __syncthreads();
        s[t] += v;
        __syncthreads();
    }
    if (t < B) {
        int b = s[t] - c;
        bucket_base[t] = b;
        bucket_cursor[t] = b;
    }
}

__global__ void k_bucket_scatter(const void* ei, const int* flag, int* bucket_cursor,
                                 unsigned int* packed, int E, int B) {
    __shared__ int h[NBUCK_MAX];
    __shared__ int base[NBUCK_MAX];
    int t = threadIdx.x;
    for (int i = t; i < B; i += THREADS) h[i] = 0;
    __syncthreads();
    int chunk = (E + gridDim.x - 1) / gridDim.x;
    int lo = blockIdx.x * chunk;
    int hi = min(lo + chunk, E);
    bool is64 = (*flag != 0);
    const long long* p64 = (const long long*)ei;
    const int* p32 = (const int*)ei;
    for (int e = lo + t; e < hi; e += THREADS) {
        int d = is64 ? (int)p64[(size_t)E + e] : p32[E + e];
        atomicAdd(&h[d >> 7], 1);
    }
    __syncthreads();
    for (int i = t; i < B; i += THREADS) {
        int c = h[i];
        base[i] = c ? atomicAdd(&bucket_cursor[i], c) : 0;
    }
    __syncthreads();
    for (int i = t; i < B; i += THREADS) h[i] = 0;
    __syncthreads();
    for (int e = lo + t; e < hi; e += THREADS) {
        int srcv, d;
        if (is64) { srcv = (int)p64[e]; d = (int)p64[(size_t)E + e]; }
        else      { srcv = p32[e];      d = p32[E + e]; }
        int b = d >> 7;
        int pos = base[b] + atomicAdd(&h[b], 1);
        packed[pos] = (unsigned int)srcv | ((unsigned int)(d & 127) << 25);
    }
}

__global__ void k_fine_sort(const unsigned int* __restrict__ packed,
                            const int* __restrict__ bucket_base,
                            const int* __restrict__ bucket_count_arr,
                            int* __restrict__ csr, int* __restrict__ offsets,
                            int* __restrict__ countp, float* __restrict__ dinv,
                            int n, int B) {
    __shared__ unsigned int words[CAP];
    __shared__ int srcstage[CAP];
    __shared__ int cnt[128];
    __shared__ int scanv[128];
    __shared__ int cursor[128];
    int b = blockIdx.x;
    int t = threadIdx.x;
    int base = bucket_base[b];
    int size = bucket_count_arr[b];
    if (t < 128) cnt[t] = 0;
    __syncthreads();
    for (int i0 = 0; i0 < size; i0 += THREADS) {
        int i = i0 + t;
        if (i < size) {
            unsigned int w = packed[base + i];
            if (i < CAP) words[i] = w;
            atomicAdd(&cnt[(w >> 25) & 127], 1);
        }
    }
    __syncthreads();
    if (t < 128) scanv[t] = cnt[t];
    __syncthreads();
    for (int off = 1; off < 128; off <<= 1) {
        int v = 0;
        if (t < 128 && t >= off) v = scanv[t - off];
        __syncthreads();
        if (t < 128) scanv[t] += v;
        __syncthreads();
    }
    if (t < 128) {
        int ex = scanv[t] - cnt[t];
        scanv[t] = ex;
        cursor[t] = ex;
        int node = (b << 7) + t;
        if (node < n) {
            offsets[node] = base + ex;
            countp[node] = cnt[t];
            dinv[node] = rsqrtf((float)(cnt[t] + 1));
        }
    }
    __syncthreads();
    if (size <= CAP) {
        for (int i0 = 0; i0 < size; i0 += THREADS) {
            int i = i0 + t;
            if (i < size) {
                unsigned int w = words[i];
                int d = (w >> 25) & 127;
                int rank = atomicAdd(&cursor[d], 1);
                srcstage[rank] = (int)(w & 0x1FFFFFFu);
            }
        }
        __syncthreads();
        for (int i0 = 0; i0 < size; i0 += THREADS) {
            int i = i0 + t;
            if (i < size) csr[base + i] = srcstage[i];
        }
    } else {
        for (int i0 = 0; i0 < size; i0 += THREADS) {
            int i = i0 + t;
            if (i < size) {
                unsigned int w = packed[base + i];
                int d = (w >> 25) & 127;
                int rank = atomicAdd(&cursor[d], 1);
                csr[base + rank] = (int)(w & 0x1FFFFFFu);
            }
        }
    }
}

// gemm1: rows [bx*512, +512) x cols [by*16, +16). M=2 rows/thread.
// hs1[r][c] = bf16( dinv[r] * sum_k x[r][k] * W1[k][c] )
__global__ void __launch_bounds__(THREADS, 4) k_gemm1(const float* __restrict__ x,
                                                      const float* __restrict__ W1,
                                                      const float* __restrict__ dinv,
                                                      unsigned int* __restrict__ hs1, int n) {
    __shared__ float Ws[128 * 16];                   // 8 KB
    int t = threadIdx.x;
    int by = blockIdx.y;                             // col block: cols [by*16, by*16+16)
    #pragma unroll
    for (int i = 0; i < 2; ++i) {
        int idx = t + i * THREADS;                   // 0..511
        int k = idx >> 2;
        int c4 = idx & 3;
        ((float4*)Ws)[idx] = ((const float4*)W1)[k * 16 + by * 4 + c4];
    }
    __syncthreads();

    int r0 = blockIdx.x * 512 + t;
    int r1 = r0 + 256;
    if (r0 >= n) return;
    bool v1 = (r1 < n);

    float4 acc0[4], acc1[4];
    #pragma unroll
    for (int j = 0; j < 4; ++j) {
        acc0[j] = make_float4(0.f, 0.f, 0.f, 0.f);
        acc1[j] = make_float4(0.f, 0.f, 0.f, 0.f);
    }

    const float* xrow0 = x + (size_t)r0 * 128;
    const float* xrow1 = x + (size_t)r1 * 128;
    for (int kk = 0; kk < 128; kk += 16) {
        float4 xv0[4], xv1[4];
        #pragma unroll
        for (int q = 0; q < 4; ++q) {
            xv0[q] = ((const float4*)(xrow0 + kk))[q];
            xv1[q] = v1 ? ((const float4*)(xrow1 + kk))[q] : make_float4(0.f, 0.f, 0.f, 0.f);
        }
        #pragma unroll
        for (int c = 0; c < 16; ++c) {
            const float4 u0 = xv0[c >> 2];
            const float4 u1 = xv1[c >> 2];
            const int m = c & 3;
            const float xc0 = (m == 0) ? u0.x : (m == 1) ? u0.y : (m == 2) ? u0.z : u0.w;
            const float xc1 = (m == 0) ? u1.x : (m == 1) ? u1.y : (m == 2) ? u1.z : u1.w;
            const float4* wrow = (const float4*)(Ws + (kk + c) * 16);
            #pragma unroll
            for (int j = 0; j < 4; ++j) {
                float4 w = wrow[j];
                acc0[j].x = fmaf(xc0, w.x, acc0[j].x);
                acc0[j].y = fmaf(xc0, w.y, acc0[j].y);
                acc0[j].z = fmaf(xc0, w.z, acc0[j].z);
                acc0[j].w = fmaf(xc0, w.w, acc0[j].w);
                acc1[j].x = fmaf(xc1, w.x, acc1[j].x);
                acc1[j].y = fmaf(xc1, w.y, acc1[j].y);
                acc1[j].z = fmaf(xc1, w.z, acc1[j].z);
                acc1[j].w = fmaf(xc1, w.w, acc1[j].w);
            }
        }
    }
    {
        float dv = dinv[r0];
        unsigned int* orow = hs1 + (size_t)r0 * 32 + by * 8;
        #pragma unroll
        for (int j = 0; j < 4; ++j) {
            float4 a = acc0[j];
            orow[2 * j]     = pack_bf2(a.x * dv, a.y * dv);
            orow[2 * j + 1] = pack_bf2(a.z * dv, a.w * dv);
        }
    }
    if (v1) {
        float dv = dinv[r1];
        unsigned int* orow = hs1 + (size_t)r1 * 32 + by * 8;
        #pragma unroll
        for (int j = 0; j < 4; ++j) {
            float4 a = acc1[j];
            orow[2 * j]     = pack_bf2(a.x * dv, a.y * dv);
            orow[2 * j + 1] = pack_bf2(a.z * dv, a.w * dv);
        }
    }
}

// One wave per node. 4 edge-groups x 16 lanes x (4 bf16 = 8B), unrolled x2.
__global__ void k_agg1(const unsigned int* __restrict__ hs1, const int* __restrict__ csr,
                       const int* __restrict__ offsets, const int* __restrict__ count,
                       const float* __restrict__ dinv, const float* __restrict__ b1,
                       unsigned int* __restrict__ h1post, int n) {
    int wid = threadIdx.x >> 6;
    int lane = threadIdx.x & 63;
    int node = blockIdx.x * 4 + wid;
    if (node >= n) return;
    int g  = lane >> 4;
    int f4 = lane & 15;
    int s = offsets[node];
    int c = count[node];
    const uint2* tab = (const uint2*)hs1;

    float4 a0 = make_float4(0.f, 0.f, 0.f, 0.f);
    float4 a1 = make_float4(0.f, 0.f, 0.f, 0.f);
    if (g == 0) {
        uint2 sv = tab[(size_t)node * 16 + f4];
        a0 = make_float4(bf_lo(sv.x), bf_hi(sv.x), bf_lo(sv.y), bf_hi(sv.y));
    }

    for (int j = 0; j < c; j += 8) {
        int e0 = j + g;
        int e1 = j + 4 + g;
        int i0 = s + min(e0, c - 1);
        int i1 = s + min(e1, c - 1);
        int s0 = csr[i0];
        int s1 = csr[i1];
        float m0 = (e0 < c) ? 1.f : 0.f;
        float m1 = (e1 < c) ? 1.f : 0.f;
        uint2 u0 = tab[(size_t)s0 * 16 + f4];
        uint2 u1 = tab[(size_t)s1 * 16 + f4];
        a0.x = fmaf(m0, bf_lo(u0.x), a0.x); a0.y = fmaf(m0, bf_hi(u0.x), a0.y);
        a0.z = fmaf(m0, bf_lo(u0.y), a0.z); a0.w = fmaf(m0, bf_hi(u0.y), a0.w);
        a1.x = fmaf(m1, bf_lo(u1.x), a1.x); a1.y = fmaf(m1, bf_hi(u1.x), a1.y);
        a1.z = fmaf(m1, bf_lo(u1.y), a1.z); a1.w = fmaf(m1, bf_hi(u1.y), a1.w);
    }
    a0.x += a1.x; a0.y += a1.y; a0.z += a1.z; a0.w += a1.w;
    a0.x += __shfl_xor(a0.x, 16); a0.y += __shfl_xor(a0.y, 16);
    a0.z += __shfl_xor(a0.z, 16); a0.w += __shfl_xor(a0.w, 16);
    a0.x += __shfl_xor(a0.x, 32); a0.y += __shfl_xor(a0.y, 32);
    a0.z += __shfl_xor(a0.z, 32); a0.w += __shfl_xor(a0.w, 32);

    if (g == 0) {
        float dv = dinv[node];
        float4 b = ((const float4*)b1)[f4];
        float ox = fmaxf(fmaf(dv, a0.x, b.x), 0.f);
        float oy = fmaxf(fmaf(dv, a0.y, b.y), 0.f);
        float oz = fmaxf(fmaf(dv, a0.z, b.z), 0.f);
        float ow = fmaxf(fmaf(dv, a0.w, b.w), 0.f);
        uint2 o;
        o.x = pack_bf2(ox, oy);
        o.y = pack_bf2(oz, ow);
        ((uint2*)h1post)[(size_t)node * 16 + f4] = o;
    }
}

// gemm2: rows [bx*512, +512) x cols [by*16, +16). M=2 rows/thread, K chunked by 16.
__global__ void __launch_bounds__(THREADS, 4) k_gemm2(const unsigned int* __restrict__ h1,
                                                      const float* __restrict__ W2,
                                                      const float* __restrict__ dinv,
                                                      unsigned int* __restrict__ hs2, int n) {
    __shared__ float Ws[64 * 16];                    // 4 KB
    int t = threadIdx.x;
    int by = blockIdx.y;
    {
        int k = t >> 2;
        int c4 = t & 3;
        ((float4*)Ws)[t] = ((const float4*)W2)[k * 8 + by * 4 + c4];
    }
    __syncthreads();

    int r0 = blockIdx.x * 512 + t;
    int r1 = r0 + 256;
    if (r0 >= n) return;
    bool v1 = (r1 < n);

    float4 acc0[4], acc1[4];
    #pragma unroll
    for (int j = 0; j < 4; ++j) {
        acc0[j] = make_float4(0.f, 0.f, 0.f, 0.f);
        acc1[j] = make_float4(0.f, 0.f, 0.f, 0.f);
    }

    const uint4* xrow0 = (const uint4*)(h1 + (size_t)r0 * 32);
    const uint4* xrow1 = (const uint4*)(h1 + (size_t)r1 * 32);
    for (int kk = 0; kk < 64; kk += 16) {
        uint4 ua0 = xrow0[(kk >> 3)];
        uint4 ub0 = xrow0[(kk >> 3) + 1];
        uint4 ua1 = v1 ? xrow1[(kk >> 3)]     : make_uint4(0u, 0u, 0u, 0u);
        uint4 ub1 = v1 ? xrow1[(kk >> 3) + 1] : make_uint4(0u, 0u, 0u, 0u);
        float xs0[16], xs1[16];
        xs0[0]=bf_lo(ua0.x); xs0[1]=bf_hi(ua0.x); xs0[2]=bf_lo(ua0.y); xs0[3]=bf_hi(ua0.y);
        xs0[4]=bf_lo(ua0.z); xs0[5]=bf_hi(ua0.z); xs0[6]=bf_lo(ua0.w); xs0[7]=bf_hi(ua0.w);
        xs0[8]=bf_lo(ub0.x); xs0[9]=bf_hi(ub0.x); xs0[10]=bf_lo(ub0.y); xs0[11]=bf_hi(ub0.y);
        xs0[12]=bf_lo(ub0.z); xs0[13]=bf_hi(ub0.z); xs0[14]=bf_lo(ub0.w); xs0[15]=bf_hi(ub0.w);
        xs1[0]=bf_lo(ua1.x); xs1[1]=bf_hi(ua1.x); xs1[2]=bf_lo(ua1.y); xs1[3]=bf_hi(ua1.y);
        xs1[4]=bf_lo(ua1.z); xs1[5]=bf_hi(ua1.z); xs1[6]=bf_lo(ua1.w); xs1[7]=bf_hi(ua1.w);
        xs1[8]=bf_lo(ub1.x); xs1[9]=bf_hi(ub1.x); xs1[10]=bf_lo(ub1.y); xs1[11]=bf_hi(ub1.y);
        xs1[12]=bf_lo(ub1.z); xs1[13]=bf_hi(ub1.z); xs1[14]=bf_lo(ub1.w); xs1[15]=bf_hi(ub1.w);
        #pragma unroll
        for (int c = 0; c < 16; ++c) {
            const float xc0 = xs0[c];
            const float xc1 = xs1[c];
            const float4* wrow = (const float4*)(Ws + (kk + c) * 16);
            #pragma unroll
            for (int j = 0; j < 4; ++j) {
                float4 w = wrow[j];
                acc0[j].x = fmaf(xc0, w.x, acc0[j].x);
                acc0[j].y = fmaf(xc0, w.y, acc0[j].y);
                acc0[j].z = fmaf(xc0, w.z, acc0[j].z);
                acc0[j].w = fmaf(xc0, w.w, acc0[j].w);
                acc1[j].x = fmaf(xc1, w.x, acc1[j].x);
                acc1[j].y = fmaf(xc1, w.y, acc1[j].y);
                acc1[j].z = fmaf(xc1, w.z, acc1[j].z);
                acc1[j].w = fmaf(xc1, w.w, acc1[j].w);
            }
        }
    }
    {
        float dv = dinv[r0];
        unsigned int* orow = hs2 + (size_t)r0 * 16 + by * 8;
        #pragma unroll
        for (int j = 0; j < 4; ++j) {
            float4 a = acc0[j];
            orow[2 * j]     = pack_bf2(a.x * dv, a.y * dv);
            orow[2 * j + 1] = pack_bf2(a.z * dv, a.w * dv);
        }
    }
    if (v1) {
        float dv = dinv[r1];
        unsigned int* orow = hs2 + (size_t)r1 * 16 + by * 8;
        #pragma unroll
        for (int j = 0; j < 4; ++j) {
            float4 a = acc1[j];
            orow[2 * j]     = pack_bf2(a.x * dv, a.y * dv);
            orow[2 * j + 1] = pack_bf2(a.z * dv, a.w * dv);
        }
    }
}

// One wave per node. 8 edge-groups x 8 lanes x (4 bf16 = 8B), unrolled x2. Fused head.
__global__ void k_agg2_head(const unsigned int* __restrict__ hs2, const int* __restrict__ csr,
                            const int* __restrict__ offsets, const int* __restrict__ count,
                            const float* __restrict__ dinv, const float* __restrict__ b2,
                            const float* __restrict__ Wfc, const float* __restrict__ bfc,
                            float* __restrict__ out, int n) {
    int wid = threadIdx.x >> 6;
    int lane = threadIdx.x & 63;
    int node = blockIdx.x * 4 + wid;
    if (node >= n) return;
    int g  = lane >> 3;
    int f4 = lane & 7;
    int s = offsets[node];
    int c = count[node];
    const uint2* tab = (const uint2*)hs2;

    float4 a0 = make_float4(0.f, 0.f, 0.f, 0.f);
    float4 a1 = make_float4(0.f, 0.f, 0.f, 0.f);
    if (g == 0) {
        uint2 sv = tab[(size_t)node * 8 + f4];
        a0 = make_float4(bf_lo(sv.x), bf_hi(sv.x), bf_lo(sv.y), bf_hi(sv.y));
    }

    for (int j = 0; j < c; j += 16) {
        int e0 = j + g;
        int e1 = j + 8 + g;
        int i0 = s + min(e0, c - 1);
        int i1 = s + min(e1, c - 1);
        int s0 = csr[i0];
        int s1 = csr[i1];
        float m0 = (e0 < c) ? 1.f : 0.f;
        float m1 = (e1 < c) ? 1.f : 0.f;
        uint2 u0 = tab[(size_t)s0 * 8 + f4];
        uint2 u1 = tab[(size_t)s1 * 8 + f4];
        a0.x = fmaf(m0, bf_lo(u0.x), a0.x); a0.y = fmaf(m0, bf_hi(u0.x), a0.y);
        a0.z = fmaf(m0, bf_lo(u0.y), a0.z); a0.w = fmaf(m0, bf_hi(u0.y), a0.w);
        a1.x = fmaf(m1, bf_lo(u1.x), a1.x); a1.y = fmaf(m1, bf_hi(u1.x), a1.y);
        a1.z = fmaf(m1, bf_lo(u1.y), a1.z); a1.w = fmaf(m1, bf_hi(u1.y), a1.w);
    }
    a0.x += a1.x; a0.y += a1.y; a0.z += a1.z; a0.w += a1.w;
    #pragma unroll
    for (int m = 8; m <= 32; m <<= 1) {
        a0.x += __shfl_xor(a0.x, m); a0.y += __shfl_xor(a0.y, m);
        a0.z += __shfl_xor(a0.z, m); a0.w += __shfl_xor(a0.w, m);
    }

    float dv = dinv[node];
    float4 b = ((const float4*)b2)[f4];
    float4 w = ((const float4*)Wfc)[f4];
    float hx = fmaxf(fmaf(dv, a0.x, b.x), 0.f);
    float hy = fmaxf(fmaf(dv, a0.y, b.y), 0.f);
    float hz = fmaxf(fmaf(dv, a0.z, b.z), 0.f);
    float hw = fmaxf(fmaf(dv, a0.w, b.w), 0.f);
    float p = hx * w.x + hy * w.y + hz * w.z + hw * w.w;
    p += __shfl_xor(p, 1);
    p += __shfl_xor(p, 2);
    p += __shfl_xor(p, 4);
    if (lane == 0) out[node] = p + bfc[0];
}

extern "C" void kernel_launch(void* const* d_in, const int* in_sizes, int n_in,
                              void* d_out, int out_size, void* d_ws, size_t ws_size,
                              hipStream_t stream) {
    const float* x   = (const float*)d_in[0];
    const void*  ei  = d_in[1];
    const float* W1  = (const float*)d_in[2];
    const float* b1  = (const float*)d_in[3];
    const float* W2  = (const float*)d_in[4];
    const float* b2  = (const float*)d_in[5];
    const float* Wfc = (const float*)d_in[6];
    const float* bfc = (const float*)d_in[7];
    float* out = (float*)d_out;

    const int n = in_sizes[0] / 128;                 // 100000
    const int E = in_sizes[1] / 2;                   // 1600000
    const int B = (n + 127) >> 7;                    // 782 buckets

    size_t off = 0;
    auto alloc = [&](size_t bytes) -> void* {
        void* p = (char*)d_ws + off;
        off += (bytes + 255) & ~(size_t)255;
        return p;
    };
    int*   bucket_count  = (int*)alloc((size_t)NBUCK_MAX * 4);
    int*   bucket_base   = (int*)alloc((size_t)NBUCK_MAX * 4);
    int*   bucket_cursor = (int*)alloc((size_t)NBUCK_MAX * 4);
    unsigned int* packed = (unsigned int*)alloc((size_t)E * 4);
    int*   csr     = (int*)  alloc((size_t)E * 4);
    int*   offsets = (int*)  alloc((size_t)n * 4);
    int*   count   = (int*)  alloc((size_t)n * 4);
    float* dinv    = (float*)alloc((size_t)n * 4);
    unsigned int* hs1    = (unsigned int*)alloc((size_t)n * 64 * 2);  // bf16
    unsigned int* h1post = (unsigned int*)alloc((size_t)n * 64 * 2);  // bf16
    unsigned int* hs2    = (unsigned int*)alloc((size_t)n * 32 * 2);  // bf16
    int*   flag    = (int*)  alloc(4);
    (void)ws_size;

    const int RB = (n + 511) / 512;                  // 196 row blocks (M=2)
    const int AG = (n + 3) / 4;

    k_detect_dtype<<<1, 1, 0, stream>>>((const unsigned int*)ei, flag);
    k_zero_int<<<(B + THREADS - 1) / THREADS, THREADS, 0, stream>>>(bucket_count, B);
    k_bucket_hist<<<SORT_BLOCKS, THREADS, 0, stream>>>(ei, flag, bucket_count, E, B);
    k_bucket_scan<<<1, 1024, 0, stream>>>(bucket_count, bucket_base, bucket_cursor, B);
    k_bucket_scatter<<<SORT_BLOCKS, THREADS, 0, stream>>>(ei, flag, bucket_cursor, packed, E, B);
    k_fine_sort<<<B, THREADS, 0, stream>>>(packed, bucket_base, bucket_count,
                                           csr, offsets, count, dinv, n, B);
    k_gemm1<<<dim3(RB, 4), THREADS, 0, stream>>>(x, W1, dinv, hs1, n);
    k_agg1<<<AG, THREADS, 0, stream>>>(hs1, csr, offsets, count, dinv, b1, h1post, n);
    k_gemm2<<<dim3(RB, 2), THREADS, 0, stream>>>(h1post, W2, dinv, hs2, n);
    k_agg2_head<<<AG, THREADS, 0, stream>>>(hs2, csr, offsets, count, dinv, b2, Wfc, bfc, out, n);
}

// Round 7
// 166.904 us; speedup vs baseline: 1.5566x; 1.5566x over previous
//
#include <hip/hip_runtime.h>
#include <hip/hip_bf16.h>
#include <stdint.h>

// GCN 2-layer + linear head. bf16 node tables + MFMA GEMMs (16x16x32 bf16).
// CSR build = two-level bucket counting sort (no scattered global atomics).
// agg kernels: wave/node gather with multi-edge ILP (round-5 proven config).

#define THREADS 256
#define NBUCK_MAX 1024
#define SORT_BLOCKS 200
#define CAP 4096

typedef __attribute__((ext_vector_type(8))) short short8;
typedef __attribute__((ext_vector_type(4))) float f32x4;
union frag_u { uint4 u4; short8 s8; };

__device__ __forceinline__ unsigned int pack_bf2(float a, float b) {
    unsigned int ua = __float_as_uint(a);
    unsigned int ub = __float_as_uint(b);
    ua = (ua + 0x7FFFu + ((ua >> 16) & 1u)) >> 16;
    ub = (ub + 0x7FFFu + ((ub >> 16) & 1u)) >> 16;
    return ua | (ub << 16);
}
__device__ __forceinline__ unsigned short bf16r(float a) {
    unsigned int ua = __float_as_uint(a);
    return (unsigned short)((ua + 0x7FFFu + ((ua >> 16) & 1u)) >> 16);
}
__device__ __forceinline__ float bf_lo(unsigned int u) { return __uint_as_float(u << 16); }
__device__ __forceinline__ float bf_hi(unsigned int u) { return __uint_as_float(u & 0xFFFF0000u); }

__global__ void k_detect_dtype(const unsigned int* ei_words, int* flag) {
    int is64 = 1;
    for (int i = 1; i < 64; i += 2) {
        if (ei_words[i] != 0u) { is64 = 0; break; }
    }
    *flag = is64;
}

__global__ void k_zero_int(int* p, int n) {
    int i = blockIdx.x * blockDim.x + threadIdx.x;
    if (i < n) p[i] = 0;
}

// Prepack W1/W2 into per-lane MFMA B-fragment layout, bf16.
// B-frag (16x16x32): lane l, elem e -> B[k][c], k = kt*32 + (l>>4)*8 + e, c = ct*16 + (l&15).
// w1f[(ct*4+kt)*64 + l] : uint4 (8 bf16).  w2f[(ct*2+kt)*64 + l].
__global__ void k_packW(const float* __restrict__ W1, const float* __restrict__ W2,
                        uint4* __restrict__ w1f, uint4* __restrict__ w2f) {
    int t = threadIdx.x;
    for (int i = t; i < 1024; i += 256) {
        int l = i & 63;
        int f = i >> 6;                 // ct*4 + kt
        int ct = f >> 2, kt = f & 3;
        int c = ct * 16 + (l & 15);
        int k0 = kt * 32 + (l >> 4) * 8;
        unsigned int r0 = pack_bf2(W1[(k0 + 0) * 64 + c], W1[(k0 + 1) * 64 + c]);
        unsigned int r1 = pack_bf2(W1[(k0 + 2) * 64 + c], W1[(k0 + 3) * 64 + c]);
        unsigned int r2 = pack_bf2(W1[(k0 + 4) * 64 + c], W1[(k0 + 5) * 64 + c]);
        unsigned int r3 = pack_bf2(W1[(k0 + 6) * 64 + c], W1[(k0 + 7) * 64 + c]);
        w1f[i] = make_uint4(r0, r1, r2, r3);
    }
    {
        int l = t & 63;
        int f = t >> 6;                 // ct*2 + kt
        int ct = f >> 1, kt = f & 1;
        int c = ct * 16 + (l & 15);
        int k0 = kt * 32 + (l >> 4) * 8;
        unsigned int r0 = pack_bf2(W2[(k0 + 0) * 32 + c], W2[(k0 + 1) * 32 + c]);
        unsigned int r1 = pack_bf2(W2[(k0 + 2) * 32 + c], W2[(k0 + 3) * 32 + c]);
        unsigned int r2 = pack_bf2(W2[(k0 + 4) * 32 + c], W2[(k0 + 5) * 32 + c]);
        unsigned int r3 = pack_bf2(W2[(k0 + 6) * 32 + c], W2[(k0 + 7) * 32 + c]);
        w2f[t] = make_uint4(r0, r1, r2, r3);
    }
}

__global__ void k_bucket_hist(const void* ei, const int* flag, int* bucket_count, int E, int B) {
    __shared__ int h[NBUCK_MAX];
    int t = threadIdx.x;
    for (int i = t; i < B; i += THREADS) h[i] = 0;
    __syncthreads();
    int chunk = (E + gridDim.x - 1) / gridDim.x;
    int lo = blockIdx.x * chunk;
    int hi = min(lo + chunk, E);
    bool is64 = (*flag != 0);
    const long long* p64 = (const long long*)ei;
    const int* p32 = (const int*)ei;
    for (int e = lo + t; e < hi; e += THREADS) {
        int d = is64 ? (int)p64[(size_t)E + e] : p32[E + e];
        atomicAdd(&h[d >> 7], 1);
    }
    __syncthreads();
    for (int i = t; i < B; i += THREADS) {
        int c = h[i];
        if (c) atomicAdd(&bucket_count[i], c);
    }
}

__global__ void k_bucket_scan(const int* bucket_count, int* bucket_base, int* bucket_cursor, int B) {
    __shared__ int s[1024];
    int t = threadIdx.x;
    int c = (t < B) ? bucket_count[t] : 0;
    s[t] = c;
    __syncthreads();
    for (int off = 1; off < 1024; off <<= 1) {
        int v = (t >= off) ? s[t - off] : 0;
        __syncthreads();
        s[t] += v;
        __syncthreads();
    }
    if (t < B) {
        int b = s[t] - c;
        bucket_base[t] = b;
        bucket_cursor[t] = b;
    }
}

__global__ void k_bucket_scatter(const void* ei, const int* flag, int* bucket_cursor,
                                 unsigned int* packed, int E, int B) {
    __shared__ int h[NBUCK_MAX];
    __shared__ int base[NBUCK_MAX];
    int t = threadIdx.x;
    for (int i = t; i < B; i += THREADS) h[i] = 0;
    __syncthreads();
    int chunk = (E + gridDim.x - 1) / gridDim.x;
    int lo = blockIdx.x * chunk;
    int hi = min(lo + chunk, E);
    bool is64 = (*flag != 0);
    const long long* p64 = (const long long*)ei;
    const int* p32 = (const int*)ei;
    for (int e = lo + t; e < hi; e += THREADS) {
        int d = is64 ? (int)p64[(size_t)E + e] : p32[E + e];
        atomicAdd(&h[d >> 7], 1);
    }
    __syncthreads();
    for (int i = t; i < B; i += THREADS) {
        int c = h[i];
        base[i] = c ? atomicAdd(&bucket_cursor[i], c) : 0;
    }
    __syncthreads();
    for (int i = t; i < B; i += THREADS) h[i] = 0;
    __syncthreads();
    for (int e = lo + t; e < hi; e += THREADS) {
        int srcv, d;
        if (is64) { srcv = (int)p64[e]; d = (int)p64[(size_t)E + e]; }
        else      { srcv = p32[e];      d = p32[E + e]; }
        int b = d >> 7;
        int pos = base[b] + atomicAdd(&h[b], 1);
        packed[pos] = (unsigned int)srcv | ((unsigned int)(d & 127) << 25);
    }
}

__global__ void k_fine_sort(const unsigned int* __restrict__ packed,
                            const int* __restrict__ bucket_base,
                            const int* __restrict__ bucket_count_arr,
                            int* __restrict__ csr, int* __restrict__ offsets,
                            int* __restrict__ countp, float* __restrict__ dinv,
                            int n, int B) {
    __shared__ unsigned int words[CAP];
    __shared__ int srcstage[CAP];
    __shared__ int cnt[128];
    __shared__ int scanv[128];
    __shared__ int cursor[128];
    int b = blockIdx.x;
    int t = threadIdx.x;
    int base = bucket_base[b];
    int size = bucket_count_arr[b];
    if (t < 128) cnt[t] = 0;
    __syncthreads();
    for (int i0 = 0; i0 < size; i0 += THREADS) {
        int i = i0 + t;
        if (i < size) {
            unsigned int w = packed[base + i];
            if (i < CAP) words[i] = w;
            atomicAdd(&cnt[(w >> 25) & 127], 1);
        }
    }
    __syncthreads();
    if (t < 128) scanv[t] = cnt[t];
    __syncthreads();
    for (int off = 1; off < 128; off <<= 1) {
        int v = 0;
        if (t < 128 && t >= off) v = scanv[t - off];
        __syncthreads();
        if (t < 128) scanv[t] += v;
        __syncthreads();
    }
    if (t < 128) {
        int ex = scanv[t] - cnt[t];
        scanv[t] = ex;
        cursor[t] = ex;
        int node = (b << 7) + t;
        if (node < n) {
            offsets[node] = base + ex;
            countp[node] = cnt[t];
            dinv[node] = rsqrtf((float)(cnt[t] + 1));
        }
    }
    __syncthreads();
    if (size <= CAP) {
        for (int i0 = 0; i0 < size; i0 += THREADS) {
            int i = i0 + t;
            if (i < size) {
                unsigned int w = words[i];
                int d = (w >> 25) & 127;
                int rank = atomicAdd(&cursor[d], 1);
                srcstage[rank] = (int)(w & 0x1FFFFFFu);
            }
        }
        __syncthreads();
        for (int i0 = 0; i0 < size; i0 += THREADS) {
            int i = i0 + t;
            if (i < size) csr[base + i] = srcstage[i];
        }
    } else {
        for (int i0 = 0; i0 < size; i0 += THREADS) {
            int i = i0 + t;
            if (i < size) {
                unsigned int w = packed[base + i];
                int d = (w >> 25) & 127;
                int rank = atomicAdd(&cursor[d], 1);
                csr[base + rank] = (int)(w & 0x1FFFFFFu);
            }
        }
    }
}

// MFMA gemm1: block = 4 waves = 64 rows; full 64 cols; K=128.
// hs1[r][c] = bf16( dinv[r] * sum_k x[r][k] * W1[k][c] )
__global__ void __launch_bounds__(THREADS) k_gemm1(const float* __restrict__ x,
                                                   const uint4* __restrict__ w1f,
                                                   const float* __restrict__ dinv,
                                                   unsigned short* __restrict__ hs1, int n) {
    int t = threadIdx.x;
    int w = t >> 6, l = t & 63;
    int rowbase = blockIdx.x * 64 + w * 16;

    uint4 bfr[16];
    #pragma unroll
    for (int f = 0; f < 16; ++f) bfr[f] = w1f[f * 64 + l];

    f32x4 acc[4];
    #pragma unroll
    for (int ct = 0; ct < 4; ++ct) acc[ct] = (f32x4){0.f, 0.f, 0.f, 0.f};

    int arow = rowbase + (l & 15);
    bool rv = (arow < n);
    const float* xp = x + (size_t)arow * 128 + (l >> 4) * 8;

    #pragma unroll
    for (int kt = 0; kt < 4; ++kt) {
        float4 a0 = make_float4(0.f, 0.f, 0.f, 0.f), a1 = a0;
        if (rv) {
            a0 = ((const float4*)(xp + kt * 32))[0];
            a1 = ((const float4*)(xp + kt * 32))[1];
        }
        frag_u af;
        af.u4 = make_uint4(pack_bf2(a0.x, a0.y), pack_bf2(a0.z, a0.w),
                           pack_bf2(a1.x, a1.y), pack_bf2(a1.z, a1.w));
        #pragma unroll
        for (int ct = 0; ct < 4; ++ct) {
            frag_u bfu; bfu.u4 = bfr[ct * 4 + kt];
            acc[ct] = __builtin_amdgcn_mfma_f32_16x16x32_bf16(af.s8, bfu.s8, acc[ct], 0, 0, 0);
        }
    }

    int orow0 = rowbase + (l >> 4) * 4;
    #pragma unroll
    for (int reg = 0; reg < 4; ++reg) {
        int r = orow0 + reg;
        if (r < n) {
            float dv = dinv[r];
            #pragma unroll
            for (int ct = 0; ct < 4; ++ct)
                hs1[(size_t)r * 64 + ct * 16 + (l & 15)] = bf16r(acc[ct][reg] * dv);
        }
    }
}

// One wave per node. 4 edge-groups x 16 lanes x (4 bf16 = 8B), unrolled x2.
__global__ void k_agg1(const unsigned int* __restrict__ hs1, const int* __restrict__ csr,
                       const int* __restrict__ offsets, const int* __restrict__ count,
                       const float* __restrict__ dinv, const float* __restrict__ b1,
                       unsigned int* __restrict__ h1post, int n) {
    int wid = threadIdx.x >> 6;
    int lane = threadIdx.x & 63;
    int node = blockIdx.x * 4 + wid;
    if (node >= n) return;
    int g  = lane >> 4;
    int f4 = lane & 15;
    int s = offsets[node];
    int c = count[node];
    const uint2* tab = (const uint2*)hs1;

    float4 a0 = make_float4(0.f, 0.f, 0.f, 0.f);
    float4 a1 = make_float4(0.f, 0.f, 0.f, 0.f);
    if (g == 0) {
        uint2 sv = tab[(size_t)node * 16 + f4];
        a0 = make_float4(bf_lo(sv.x), bf_hi(sv.x), bf_lo(sv.y), bf_hi(sv.y));
    }

    for (int j = 0; j < c; j += 8) {
        int e0 = j + g;
        int e1 = j + 4 + g;
        int i0 = s + min(e0, c - 1);
        int i1 = s + min(e1, c - 1);
        int s0 = csr[i0];
        int s1 = csr[i1];
        float m0 = (e0 < c) ? 1.f : 0.f;
        float m1 = (e1 < c) ? 1.f : 0.f;
        uint2 u0 = tab[(size_t)s0 * 16 + f4];
        uint2 u1 = tab[(size_t)s1 * 16 + f4];
        a0.x = fmaf(m0, bf_lo(u0.x), a0.x); a0.y = fmaf(m0, bf_hi(u0.x), a0.y);
        a0.z = fmaf(m0, bf_lo(u0.y), a0.z); a0.w = fmaf(m0, bf_hi(u0.y), a0.w);
        a1.x = fmaf(m1, bf_lo(u1.x), a1.x); a1.y = fmaf(m1, bf_hi(u1.x), a1.y);
        a1.z = fmaf(m1, bf_lo(u1.y), a1.z); a1.w = fmaf(m1, bf_hi(u1.y), a1.w);
    }
    a0.x += a1.x; a0.y += a1.y; a0.z += a1.z; a0.w += a1.w;
    a0.x += __shfl_xor(a0.x, 16); a0.y += __shfl_xor(a0.y, 16);
    a0.z += __shfl_xor(a0.z, 16); a0.w += __shfl_xor(a0.w, 16);
    a0.x += __shfl_xor(a0.x, 32); a0.y += __shfl_xor(a0.y, 32);
    a0.z += __shfl_xor(a0.z, 32); a0.w += __shfl_xor(a0.w, 32);

    if (g == 0) {
        float dv = dinv[node];
        float4 b = ((const float4*)b1)[f4];
        float ox = fmaxf(fmaf(dv, a0.x, b.x), 0.f);
        float oy = fmaxf(fmaf(dv, a0.y, b.y), 0.f);
        float oz = fmaxf(fmaf(dv, a0.z, b.z), 0.f);
        float ow = fmaxf(fmaf(dv, a0.w, b.w), 0.f);
        uint2 o;
        o.x = pack_bf2(ox, oy);
        o.y = pack_bf2(oz, ow);
        ((uint2*)h1post)[(size_t)node * 16 + f4] = o;
    }
}

// MFMA gemm2: block = 4 waves = 64 rows; 32 cols; K=64. A = h1post (bf16).
__global__ void __launch_bounds__(THREADS) k_gemm2(const uint4* __restrict__ h1,
                                                   const uint4* __restrict__ w2f,
                                                   const float* __restrict__ dinv,
                                                   unsigned short* __restrict__ hs2, int n) {
    int t = threadIdx.x;
    int w = t >> 6, l = t & 63;
    int rowbase = blockIdx.x * 64 + w * 16;

    uint4 bfr[4];
    #pragma unroll
    for (int f = 0; f < 4; ++f) bfr[f] = w2f[f * 64 + l];

    f32x4 acc[2];
    acc[0] = (f32x4){0.f, 0.f, 0.f, 0.f};
    acc[1] = (f32x4){0.f, 0.f, 0.f, 0.f};

    int arow = rowbase + (l & 15);
    bool rv = (arow < n);
    const uint4* hp = h1 + (size_t)arow * 8 + (l >> 4);   // row = 8 uint4 (64 bf16)

    #pragma unroll
    for (int kt = 0; kt < 2; ++kt) {
        frag_u af;
        af.u4 = rv ? hp[kt * 4] : make_uint4(0u, 0u, 0u, 0u);
        #pragma unroll
        for (int ct = 0; ct < 2; ++ct) {
            frag_u bfu; bfu.u4 = bfr[ct * 2 + kt];
            acc[ct] = __builtin_amdgcn_mfma_f32_16x16x32_bf16(af.s8, bfu.s8, acc[ct], 0, 0, 0);
        }
    }

    int orow0 = rowbase + (l >> 4) * 4;
    #pragma unroll
    for (int reg = 0; reg < 4; ++reg) {
        int r = orow0 + reg;
        if (r < n) {
            float dv = dinv[r];
            #pragma unroll
            for (int ct = 0; ct < 2; ++ct)
                hs2[(size_t)r * 32 + ct * 16 + (l & 15)] = bf16r(acc[ct][reg] * dv);
        }
    }
}

// One wave per node. 8 edge-groups x 8 lanes x (4 bf16 = 8B), unrolled x2. Fused head.
__global__ void k_agg2_head(const unsigned int* __restrict__ hs2, const int* __restrict__ csr,
                            const int* __restrict__ offsets, const int* __restrict__ count,
                            const float* __restrict__ dinv, const float* __restrict__ b2,
                            const float* __restrict__ Wfc, const float* __restrict__ bfc,
                            float* __restrict__ out, int n) {
    int wid = threadIdx.x >> 6;
    int lane = threadIdx.x & 63;
    int node = blockIdx.x * 4 + wid;
    if (node >= n) return;
    int g  = lane >> 3;
    int f4 = lane & 7;
    int s = offsets[node];
    int c = count[node];
    const uint2* tab = (const uint2*)hs2;

    float4 a0 = make_float4(0.f, 0.f, 0.f, 0.f);
    float4 a1 = make_float4(0.f, 0.f, 0.f, 0.f);
    if (g == 0) {
        uint2 sv = tab[(size_t)node * 8 + f4];
        a0 = make_float4(bf_lo(sv.x), bf_hi(sv.x), bf_lo(sv.y), bf_hi(sv.y));
    }

    for (int j = 0; j < c; j += 16) {
        int e0 = j + g;
        int e1 = j + 8 + g;
        int i0 = s + min(e0, c - 1);
        int i1 = s + min(e1, c - 1);
        int s0 = csr[i0];
        int s1 = csr[i1];
        float m0 = (e0 < c) ? 1.f : 0.f;
        float m1 = (e1 < c) ? 1.f : 0.f;
        uint2 u0 = tab[(size_t)s0 * 8 + f4];
        uint2 u1 = tab[(size_t)s1 * 8 + f4];
        a0.x = fmaf(m0, bf_lo(u0.x), a0.x); a0.y = fmaf(m0, bf_hi(u0.x), a0.y);
        a0.z = fmaf(m0, bf_lo(u0.y), a0.z); a0.w = fmaf(m0, bf_hi(u0.y), a0.w);
        a1.x = fmaf(m1, bf_lo(u1.x), a1.x); a1.y = fmaf(m1, bf_hi(u1.x), a1.y);
        a1.z = fmaf(m1, bf_lo(u1.y), a1.z); a1.w = fmaf(m1, bf_hi(u1.y), a1.w);
    }
    a0.x += a1.x; a0.y += a1.y; a0.z += a1.z; a0.w += a1.w;
    #pragma unroll
    for (int m = 8; m <= 32; m <<= 1) {
        a0.x += __shfl_xor(a0.x, m); a0.y += __shfl_xor(a0.y, m);
        a0.z += __shfl_xor(a0.z, m); a0.w += __shfl_xor(a0.w, m);
    }

    float dv = dinv[node];
    float4 b = ((const float4*)b2)[f4];
    float4 w = ((const float4*)Wfc)[f4];
    float hx = fmaxf(fmaf(dv, a0.x, b.x), 0.f);
    float hy = fmaxf(fmaf(dv, a0.y, b.y), 0.f);
    float hz = fmaxf(fmaf(dv, a0.z, b.z), 0.f);
    float hw = fmaxf(fmaf(dv, a0.w, b.w), 0.f);
    float p = hx * w.x + hy * w.y + hz * w.z + hw * w.w;
    p += __shfl_xor(p, 1);
    p += __shfl_xor(p, 2);
    p += __shfl_xor(p, 4);
    if (lane == 0) out[node] = p + bfc[0];
}

extern "C" void kernel_launch(void* const* d_in, const int* in_sizes, int n_in,
                              void* d_out, int out_size, void* d_ws, size_t ws_size,
                              hipStream_t stream) {
    const float* x   = (const float*)d_in[0];
    const void*  ei  = d_in[1];
    const float* W1  = (const float*)d_in[2];
    const float* b1  = (const float*)d_in[3];
    const float* W2  = (const float*)d_in[4];
    const float* b2  = (const float*)d_in[5];
    const float* Wfc = (const float*)d_in[6];
    const float* bfc = (const float*)d_in[7];
    float* out = (float*)d_out;

    const int n = in_sizes[0] / 128;                 // 100000
    const int E = in_sizes[1] / 2;                   // 1600000
    const int B = (n + 127) >> 7;                    // 782 buckets

    size_t off = 0;
    auto alloc = [&](size_t bytes) -> void* {
        void* p = (char*)d_ws + off;
        off += (bytes + 255) & ~(size_t)255;
        return p;
    };
    int*   bucket_count  = (int*)alloc((size_t)NBUCK_MAX * 4);
    int*   bucket_base   = (int*)alloc((size_t)NBUCK_MAX * 4);
    int*   bucket_cursor = (int*)alloc((size_t)NBUCK_MAX * 4);
    unsigned int* packed = (unsigned int*)alloc((size_t)E * 4);
    int*   csr     = (int*)  alloc((size_t)E * 4);
    int*   offsets = (int*)  alloc((size_t)n * 4);
    int*   count   = (int*)  alloc((size_t)n * 4);
    float* dinv    = (float*)alloc((size_t)n * 4);
    unsigned int* hs1    = (unsigned int*)alloc((size_t)n * 64 * 2);  // bf16
    unsigned int* h1post = (unsigned int*)alloc((size_t)n * 64 * 2);  // bf16
    unsigned int* hs2    = (unsigned int*)alloc((size_t)n * 32 * 2);  // bf16
    uint4* w1f   = (uint4*)alloc(1024 * 16);
    uint4* w2f   = (uint4*)alloc(256 * 16);
    int*   flag  = (int*)  alloc(4);
    (void)ws_size;

    const int GB = (n + 63) / 64;                    // 1563 MFMA gemm blocks
    const int AG = (n + 3) / 4;

    k_detect_dtype<<<1, 1, 0, stream>>>((const unsigned int*)ei, flag);
    k_zero_int<<<(B + THREADS - 1) / THREADS, THREADS, 0, stream>>>(bucket_count, B);
    k_packW<<<1, THREADS, 0, stream>>>(W1, W2, w1f, w2f);
    k_bucket_hist<<<SORT_BLOCKS, THREADS, 0, stream>>>(ei, flag, bucket_count, E, B);
    k_bucket_scan<<<1, 1024, 0, stream>>>(bucket_count, bucket_base, bucket_cursor, B);
    k_bucket_scatter<<<SORT_BLOCKS, THREADS, 0, stream>>>(ei, flag, bucket_cursor, packed, E, B);
    k_fine_sort<<<B, THREADS, 0, stream>>>(packed, bucket_base, bucket_count,
                                           csr, offsets, count, dinv, n, B);
    k_gemm1<<<GB, THREADS, 0, stream>>>(x, w1f, dinv, (unsigned short*)hs1, n);
    k_agg1<<<AG, THREADS, 0, stream>>>(hs1, csr, offsets, count, dinv, b1, h1post, n);
    k_gemm2<<<GB, THREADS, 0, stream>>>((const uint4*)h1post, w2f, dinv, (unsigned short*)hs2, n);
    k_agg2_head<<<AG, THREADS, 0, stream>>>(hs2, csr, offsets, count, dinv, b2, Wfc, bfc, out, n);
}

// Round 8
// 155.071 us; speedup vs baseline: 1.6754x; 1.0763x over previous
//
#include <hip/hip_runtime.h>
#include <hip/hip_bf16.h>
#include <stdint.h>

// GCN 2-layer + linear head. bf16 node tables + MFMA GEMMs (16x16x32 bf16).
// CSR build = two-level bucket counting sort (no scattered global atomics).
// agg kernels: one-shot 64-wide CSR load + __shfl broadcast -> no dependent
// index->gather chain; 16 edges in flight per wave.

#define THREADS 256
#define NBUCK_MAX 1024
#define SORT_BLOCKS 200
#define CAP 4096

typedef __attribute__((ext_vector_type(8))) short short8;
typedef __attribute__((ext_vector_type(4))) float f32x4;
union frag_u { uint4 u4; short8 s8; };

__device__ __forceinline__ unsigned int pack_bf2(float a, float b) {
    unsigned int ua = __float_as_uint(a);
    unsigned int ub = __float_as_uint(b);
    ua = (ua + 0x7FFFu + ((ua >> 16) & 1u)) >> 16;
    ub = (ub + 0x7FFFu + ((ub >> 16) & 1u)) >> 16;
    return ua | (ub << 16);
}
__device__ __forceinline__ unsigned short bf16r(float a) {
    unsigned int ua = __float_as_uint(a);
    return (unsigned short)((ua + 0x7FFFu + ((ua >> 16) & 1u)) >> 16);
}
__device__ __forceinline__ float bf_lo(unsigned int u) { return __uint_as_float(u << 16); }
__device__ __forceinline__ float bf_hi(unsigned int u) { return __uint_as_float(u & 0xFFFF0000u); }

// block 0: dtype detect; block 1: pack W1/W2 to MFMA B-frag layout; blocks 2+: zero bucket counts.
__global__ void k_prep(const unsigned int* ei_words, int* flag,
                       int* bucket_count, int B,
                       const float* __restrict__ W1, const float* __restrict__ W2,
                       uint4* __restrict__ w1f, uint4* __restrict__ w2f) {
    int b = blockIdx.x;
    int t = threadIdx.x;
    if (b == 0) {
        if (t == 0) {
            int is64 = 1;
            for (int i = 1; i < 64; i += 2) {
                if (ei_words[i] != 0u) { is64 = 0; break; }
            }
            *flag = is64;
        }
    } else if (b == 1) {
        // B-frag (16x16x32): lane l, elem e -> B[k][c], k = kt*32+(l>>4)*8+e, c = ct*16+(l&15).
        for (int i = t; i < 1024; i += THREADS) {
            int l = i & 63;
            int f = i >> 6;                 // ct*4 + kt
            int ct = f >> 2, kt = f & 3;
            int c = ct * 16 + (l & 15);
            int k0 = kt * 32 + (l >> 4) * 8;
            unsigned int r0 = pack_bf2(W1[(k0 + 0) * 64 + c], W1[(k0 + 1) * 64 + c]);
            unsigned int r1 = pack_bf2(W1[(k0 + 2) * 64 + c], W1[(k0 + 3) * 64 + c]);
            unsigned int r2 = pack_bf2(W1[(k0 + 4) * 64 + c], W1[(k0 + 5) * 64 + c]);
            unsigned int r3 = pack_bf2(W1[(k0 + 6) * 64 + c], W1[(k0 + 7) * 64 + c]);
            w1f[i] = make_uint4(r0, r1, r2, r3);
        }
        {
            int l = t & 63;
            int f = t >> 6;                 // ct*2 + kt
            int ct = f >> 1, kt = f & 1;
            int c = ct * 16 + (l & 15);
            int k0 = kt * 32 + (l >> 4) * 8;
            unsigned int r0 = pack_bf2(W2[(k0 + 0) * 32 + c], W2[(k0 + 1) * 32 + c]);
            unsigned int r1 = pack_bf2(W2[(k0 + 2) * 32 + c], W2[(k0 + 3) * 32 + c]);
            unsigned int r2 = pack_bf2(W2[(k0 + 4) * 32 + c], W2[(k0 + 5) * 32 + c]);
            unsigned int r3 = pack_bf2(W2[(k0 + 6) * 32 + c], W2[(k0 + 7) * 32 + c]);
            w2f[t] = make_uint4(r0, r1, r2, r3);
        }
    } else {
        int i = (b - 2) * THREADS + t;
        if (i < B) bucket_count[i] = 0;
    }
}

__global__ void k_bucket_hist(const void* ei, const int* flag, int* bucket_count, int E, int B) {
    __shared__ int h[NBUCK_MAX];
    int t = threadIdx.x;
    for (int i = t; i < B; i += THREADS) h[i] = 0;
    __syncthreads();
    int chunk = (E + gridDim.x - 1) / gridDim.x;
    int lo = blockIdx.x * chunk;
    int hi = min(lo + chunk, E);
    bool is64 = (*flag != 0);
    const long long* p64 = (const long long*)ei;
    const int* p32 = (const int*)ei;
    for (int e = lo + t; e < hi; e += THREADS) {
        int d = is64 ? (int)p64[(size_t)E + e] : p32[E + e];
        atomicAdd(&h[d >> 7], 1);
    }
    __syncthreads();
    for (int i = t; i < B; i += THREADS) {
        int c = h[i];
        if (c) atomicAdd(&bucket_count[i], c);
    }
}

__global__ void k_bucket_scan(const int* bucket_count, int* bucket_base, int* bucket_cursor, int B) {
    __shared__ int s[1024];
    int t = threadIdx.x;
    int c = (t < B) ? bucket_count[t] : 0;
    s[t] = c;
    __syncthreads();
    for (int off = 1; off < 1024; off <<= 1) {
        int v = (t >= off) ? s[t - off] : 0;
        __syncthreads();
        s[t] += v;
        __syncthreads();
    }
    if (t < B) {
        int b = s[t] - c;
        bucket_base[t] = b;
        bucket_cursor[t] = b;
    }
}

__global__ void k_bucket_scatter(const void* ei, const int* flag, int* bucket_cursor,
                                 unsigned int* packed, int E, int B) {
    __shared__ int h[NBUCK_MAX];
    __shared__ int base[NBUCK_MAX];
    int t = threadIdx.x;
    for (int i = t; i < B; i += THREADS) h[i] = 0;
    __syncthreads();
    int chunk = (E + gridDim.x - 1) / gridDim.x;
    int lo = blockIdx.x * chunk;
    int hi = min(lo + chunk, E);
    bool is64 = (*flag != 0);
    const long long* p64 = (const long long*)ei;
    const int* p32 = (const int*)ei;
    for (int e = lo + t; e < hi; e += THREADS) {
        int d = is64 ? (int)p64[(size_t)E + e] : p32[E + e];
        atomicAdd(&h[d >> 7], 1);
    }
    __syncthreads();
    for (int i = t; i < B; i += THREADS) {
        int c = h[i];
        base[i] = c ? atomicAdd(&bucket_cursor[i], c) : 0;
    }
    __syncthreads();
    for (int i = t; i < B; i += THREADS) h[i] = 0;
    __syncthreads();
    for (int e = lo + t; e < hi; e += THREADS) {
        int srcv, d;
        if (is64) { srcv = (int)p64[e]; d = (int)p64[(size_t)E + e]; }
        else      { srcv = p32[e];      d = p32[E + e]; }
        int b = d >> 7;
        int pos = base[b] + atomicAdd(&h[b], 1);
        packed[pos] = (unsigned int)srcv | ((unsigned int)(d & 127) << 25);
    }
}

__global__ void k_fine_sort(const unsigned int* __restrict__ packed,
                            const int* __restrict__ bucket_base,
                            const int* __restrict__ bucket_count_arr,
                            int* __restrict__ csr, int* __restrict__ offsets,
                            int* __restrict__ countp, float* __restrict__ dinv,
                            int n, int B) {
    __shared__ unsigned int words[CAP];
    __shared__ int srcstage[CAP];
    __shared__ int cnt[128];
    __shared__ int scanv[128];
    __shared__ int cursor[128];
    int b = blockIdx.x;
    int t = threadIdx.x;
    int base = bucket_base[b];
    int size = bucket_count_arr[b];
    if (t < 128) cnt[t] = 0;
    __syncthreads();
    for (int i0 = 0; i0 < size; i0 += THREADS) {
        int i = i0 + t;
        if (i < size) {
            unsigned int w = packed[base + i];
            if (i < CAP) words[i] = w;
            atomicAdd(&cnt[(w >> 25) & 127], 1);
        }
    }
    __syncthreads();
    if (t < 128) scanv[t] = cnt[t];
    __syncthreads();
    for (int off = 1; off < 128; off <<= 1) {
        int v = 0;
        if (t < 128 && t >= off) v = scanv[t - off];
        __syncthreads();
        if (t < 128) scanv[t] += v;
        __syncthreads();
    }
    if (t < 128) {
        int ex = scanv[t] - cnt[t];
        scanv[t] = ex;
        cursor[t] = ex;
        int node = (b << 7) + t;
        if (node < n) {
            offsets[node] = base + ex;
            countp[node] = cnt[t];
            dinv[node] = rsqrtf((float)(cnt[t] + 1));
        }
    }
    __syncthreads();
    if (size <= CAP) {
        for (int i0 = 0; i0 < size; i0 += THREADS) {
            int i = i0 + t;
            if (i < size) {
                unsigned int w = words[i];
                int d = (w >> 25) & 127;
                int rank = atomicAdd(&cursor[d], 1);
                srcstage[rank] = (int)(w & 0x1FFFFFFu);
            }
        }
        __syncthreads();
        for (int i0 = 0; i0 < size; i0 += THREADS) {
            int i = i0 + t;
            if (i < size) csr[base + i] = srcstage[i];
        }
    } else {
        for (int i0 = 0; i0 < size; i0 += THREADS) {
            int i = i0 + t;
            if (i < size) {
                unsigned int w = packed[base + i];
                int d = (w >> 25) & 127;
                int rank = atomicAdd(&cursor[d], 1);
                csr[base + rank] = (int)(w & 0x1FFFFFFu);
            }
        }
    }
}

// MFMA gemm1: block = 4 waves = 64 rows; full 64 cols; K=128.
__global__ void __launch_bounds__(THREADS) k_gemm1(const float* __restrict__ x,
                                                   const uint4* __restrict__ w1f,
                                                   const float* __restrict__ dinv,
                                                   unsigned short* __restrict__ hs1, int n) {
    int t = threadIdx.x;
    int w = t >> 6, l = t & 63;
    int rowbase = blockIdx.x * 64 + w * 16;

    uint4 bfr[16];
    #pragma unroll
    for (int f = 0; f < 16; ++f) bfr[f] = w1f[f * 64 + l];

    f32x4 acc[4];
    #pragma unroll
    for (int ct = 0; ct < 4; ++ct) acc[ct] = (f32x4){0.f, 0.f, 0.f, 0.f};

    int arow = rowbase + (l & 15);
    bool rv = (arow < n);
    const float* xp = x + (size_t)arow * 128 + (l >> 4) * 8;

    #pragma unroll
    for (int kt = 0; kt < 4; ++kt) {
        float4 a0 = make_float4(0.f, 0.f, 0.f, 0.f), a1 = a0;
        if (rv) {
            a0 = ((const float4*)(xp + kt * 32))[0];
            a1 = ((const float4*)(xp + kt * 32))[1];
        }
        frag_u af;
        af.u4 = make_uint4(pack_bf2(a0.x, a0.y), pack_bf2(a0.z, a0.w),
                           pack_bf2(a1.x, a1.y), pack_bf2(a1.z, a1.w));
        #pragma unroll
        for (int ct = 0; ct < 4; ++ct) {
            frag_u bfu; bfu.u4 = bfr[ct * 4 + kt];
            acc[ct] = __builtin_amdgcn_mfma_f32_16x16x32_bf16(af.s8, bfu.s8, acc[ct], 0, 0, 0);
        }
    }

    int orow0 = rowbase + (l >> 4) * 4;
    #pragma unroll
    for (int reg = 0; reg < 4; ++reg) {
        int r = orow0 + reg;
        if (r < n) {
            float dv = dinv[r];
            #pragma unroll
            for (int ct = 0; ct < 4; ++ct)
                hs1[(size_t)r * 64 + ct * 16 + (l & 15)] = bf16r(acc[ct][reg] * dv);
        }
    }
}

// One wave per node. 64-wide CSR preload + shfl broadcast; 16 edges/iter (4 groups x 4-deep).
__global__ void k_agg1(const unsigned int* __restrict__ hs1, const int* __restrict__ csr,
                       const int* __restrict__ offsets, const int* __restrict__ count,
                       const float* __restrict__ dinv, const float* __restrict__ b1,
                       unsigned int* __restrict__ h1post, int n) {
    int wid = threadIdx.x >> 6;
    int lane = threadIdx.x & 63;
    int node = blockIdx.x * 4 + wid;
    if (node >= n) return;
    int g  = lane >> 4;
    int f4 = lane & 15;
    int s = offsets[node];
    int c = count[node];
    const uint2* tab = (const uint2*)hs1;

    float4 a0 = make_float4(0.f, 0.f, 0.f, 0.f);
    float4 a1 = a0, a2 = a0, a3 = a0;
    if (g == 0) {
        uint2 sv = tab[(size_t)node * 16 + f4];
        a0 = make_float4(bf_lo(sv.x), bf_hi(sv.x), bf_lo(sv.y), bf_hi(sv.y));
    }

    for (int j0 = 0; j0 < c; j0 += 64) {
        int cc = min(c - j0, 64);
        int idx = csr[s + j0 + min(lane, cc - 1)];   // one coalesced 64-lane load
        for (int j = 0; j < cc; j += 16) {
            int e0 = j + g, e1 = e0 + 4, e2 = e0 + 8, e3 = e0 + 12;
            int s0 = __shfl(idx, min(e0, cc - 1));
            int s1 = __shfl(idx, min(e1, cc - 1));
            int s2 = __shfl(idx, min(e2, cc - 1));
            int s3 = __shfl(idx, min(e3, cc - 1));
            uint2 u0 = tab[(size_t)s0 * 16 + f4];
            uint2 u1 = tab[(size_t)s1 * 16 + f4];
            uint2 u2 = tab[(size_t)s2 * 16 + f4];
            uint2 u3 = tab[(size_t)s3 * 16 + f4];
            float m0 = (e0 < cc) ? 1.f : 0.f;
            float m1 = (e1 < cc) ? 1.f : 0.f;
            float m2 = (e2 < cc) ? 1.f : 0.f;
            float m3 = (e3 < cc) ? 1.f : 0.f;
            a0.x = fmaf(m0, bf_lo(u0.x), a0.x); a0.y = fmaf(m0, bf_hi(u0.x), a0.y);
            a0.z = fmaf(m0, bf_lo(u0.y), a0.z); a0.w = fmaf(m0, bf_hi(u0.y), a0.w);
            a1.x = fmaf(m1, bf_lo(u1.x), a1.x); a1.y = fmaf(m1, bf_hi(u1.x), a1.y);
            a1.z = fmaf(m1, bf_lo(u1.y), a1.z); a1.w = fmaf(m1, bf_hi(u1.y), a1.w);
            a2.x = fmaf(m2, bf_lo(u2.x), a2.x); a2.y = fmaf(m2, bf_hi(u2.x), a2.y);
            a2.z = fmaf(m2, bf_lo(u2.y), a2.z); a2.w = fmaf(m2, bf_hi(u2.y), a2.w);
            a3.x = fmaf(m3, bf_lo(u3.x), a3.x); a3.y = fmaf(m3, bf_hi(u3.x), a3.y);
            a3.z = fmaf(m3, bf_lo(u3.y), a3.z); a3.w = fmaf(m3, bf_hi(u3.y), a3.w);
        }
    }
    a0.x += a1.x + a2.x + a3.x;
    a0.y += a1.y + a2.y + a3.y;
    a0.z += a1.z + a2.z + a3.z;
    a0.w += a1.w + a2.w + a3.w;
    a0.x += __shfl_xor(a0.x, 16); a0.y += __shfl_xor(a0.y, 16);
    a0.z += __shfl_xor(a0.z, 16); a0.w += __shfl_xor(a0.w, 16);
    a0.x += __shfl_xor(a0.x, 32); a0.y += __shfl_xor(a0.y, 32);
    a0.z += __shfl_xor(a0.z, 32); a0.w += __shfl_xor(a0.w, 32);

    if (g == 0) {
        float dv = dinv[node];
        float4 b = ((const float4*)b1)[f4];
        float ox = fmaxf(fmaf(dv, a0.x, b.x), 0.f);
        float oy = fmaxf(fmaf(dv, a0.y, b.y), 0.f);
        float oz = fmaxf(fmaf(dv, a0.z, b.z), 0.f);
        float ow = fmaxf(fmaf(dv, a0.w, b.w), 0.f);
        uint2 o;
        o.x = pack_bf2(ox, oy);
        o.y = pack_bf2(oz, ow);
        ((uint2*)h1post)[(size_t)node * 16 + f4] = o;
    }
}

// MFMA gemm2: block = 4 waves = 64 rows; 32 cols; K=64. A = h1post (bf16).
__global__ void __launch_bounds__(THREADS) k_gemm2(const uint4* __restrict__ h1,
                                                   const uint4* __restrict__ w2f,
                                                   const float* __restrict__ dinv,
                                                   unsigned short* __restrict__ hs2, int n) {
    int t = threadIdx.x;
    int w = t >> 6, l = t & 63;
    int rowbase = blockIdx.x * 64 + w * 16;

    uint4 bfr[4];
    #pragma unroll
    for (int f = 0; f < 4; ++f) bfr[f] = w2f[f * 64 + l];

    f32x4 acc[2];
    acc[0] = (f32x4){0.f, 0.f, 0.f, 0.f};
    acc[1] = (f32x4){0.f, 0.f, 0.f, 0.f};

    int arow = rowbase + (l & 15);
    bool rv = (arow < n);
    const uint4* hp = h1 + (size_t)arow * 8 + (l >> 4);

    #pragma unroll
    for (int kt = 0; kt < 2; ++kt) {
        frag_u af;
        af.u4 = rv ? hp[kt * 4] : make_uint4(0u, 0u, 0u, 0u);
        #pragma unroll
        for (int ct = 0; ct < 2; ++ct) {
            frag_u bfu; bfu.u4 = bfr[ct * 2 + kt];
            acc[ct] = __builtin_amdgcn_mfma_f32_16x16x32_bf16(af.s8, bfu.s8, acc[ct], 0, 0, 0);
        }
    }

    int orow0 = rowbase + (l >> 4) * 4;
    #pragma unroll
    for (int reg = 0; reg < 4; ++reg) {
        int r = orow0 + reg;
        if (r < n) {
            float dv = dinv[r];
            #pragma unroll
            for (int ct = 0; ct < 2; ++ct)
                hs2[(size_t)r * 32 + ct * 16 + (l & 15)] = bf16r(acc[ct][reg] * dv);
        }
    }
}

// One wave per node. 64-wide CSR preload + shfl; 16 edges/iter (8 groups x 2-deep). Fused head.
__global__ void k_agg2_head(const unsigned int* __restrict__ hs2, const int* __restrict__ csr,
                            const int* __restrict__ offsets, const int* __restrict__ count,
                            const float* __restrict__ dinv, const float* __restrict__ b2,
                            const float* __restrict__ Wfc, const float* __restrict__ bfc,
                            float* __restrict__ out, int n) {
    int wid = threadIdx.x >> 6;
    int lane = threadIdx.x & 63;
    int node = blockIdx.x * 4 + wid;
    if (node >= n) return;
    int g  = lane >> 3;
    int f4 = lane & 7;
    int s = offsets[node];
    int c = count[node];
    const uint2* tab = (const uint2*)hs2;

    float4 a0 = make_float4(0.f, 0.f, 0.f, 0.f);
    float4 a1 = a0;
    if (g == 0) {
        uint2 sv = tab[(size_t)node * 8 + f4];
        a0 = make_float4(bf_lo(sv.x), bf_hi(sv.x), bf_lo(sv.y), bf_hi(sv.y));
    }

    for (int j0 = 0; j0 < c; j0 += 64) {
        int cc = min(c - j0, 64);
        int idx = csr[s + j0 + min(lane, cc - 1)];
        for (int j = 0; j < cc; j += 16) {
            int e0 = j + g, e1 = e0 + 8;
            int s0 = __shfl(idx, min(e0, cc - 1));
            int s1 = __shfl(idx, min(e1, cc - 1));
            uint2 u0 = tab[(size_t)s0 * 8 + f4];
            uint2 u1 = tab[(size_t)s1 * 8 + f4];
            float m0 = (e0 < cc) ? 1.f : 0.f;
            float m1 = (e1 < cc) ? 1.f : 0.f;
            a0.x = fmaf(m0, bf_lo(u0.x), a0.x); a0.y = fmaf(m0, bf_hi(u0.x), a0.y);
            a0.z = fmaf(m0, bf_lo(u0.y), a0.z); a0.w = fmaf(m0, bf_hi(u0.y), a0.w);
            a1.x = fmaf(m1, bf_lo(u1.x), a1.x); a1.y = fmaf(m1, bf_hi(u1.x), a1.y);
            a1.z = fmaf(m1, bf_lo(u1.y), a1.z); a1.w = fmaf(m1, bf_hi(u1.y), a1.w);
        }
    }
    a0.x += a1.x; a0.y += a1.y; a0.z += a1.z; a0.w += a1.w;
    #pragma unroll
    for (int m = 8; m <= 32; m <<= 1) {
        a0.x += __shfl_xor(a0.x, m); a0.y += __shfl_xor(a0.y, m);
        a0.z += __shfl_xor(a0.z, m); a0.w += __shfl_xor(a0.w, m);
    }

    float dv = dinv[node];
    float4 b = ((const float4*)b2)[f4];
    float4 w = ((const float4*)Wfc)[f4];
    float hx = fmaxf(fmaf(dv, a0.x, b.x), 0.f);
    float hy = fmaxf(fmaf(dv, a0.y, b.y), 0.f);
    float hz = fmaxf(fmaf(dv, a0.z, b.z), 0.f);
    float hw = fmaxf(fmaf(dv, a0.w, b.w), 0.f);
    float p = hx * w.x + hy * w.y + hz * w.z + hw * w.w;
    p += __shfl_xor(p, 1);
    p += __shfl_xor(p, 2);
    p += __shfl_xor(p, 4);
    if (lane == 0) out[node] = p + bfc[0];
}

extern "C" void kernel_launch(void* const* d_in, const int* in_sizes, int n_in,
                              void* d_out, int out_size, void* d_ws, size_t ws_size,
                              hipStream_t stream) {
    const float* x   = (const float*)d_in[0];
    const void*  ei  = d_in[1];
    const float* W1  = (const float*)d_in[2];
    const float* b1  = (const float*)d_in[3];
    const float* W2  = (const float*)d_in[4];
    const float* b2  = (const float*)d_in[5];
    const float* Wfc = (const float*)d_in[6];
    const float* bfc = (const float*)d_in[7];
    float* out = (float*)d_out;

    const int n = in_sizes[0] / 128;                 // 100000
    const int E = in_sizes[1] / 2;                   // 1600000
    const int B = (n + 127) >> 7;                    // 782 buckets

    size_t off = 0;
    auto alloc = [&](size_t bytes) -> void* {
        void* p = (char*)d_ws + off;
        off += (bytes + 255) & ~(size_t)255;
        return p;
    };
    int*   bucket_count  = (int*)alloc((size_t)NBUCK_MAX * 4);
    int*   bucket_base   = (int*)alloc((size_t)NBUCK_MAX * 4);
    int*   bucket_cursor = (int*)alloc((size_t)NBUCK_MAX * 4);
    unsigned int* packed = (unsigned int*)alloc((size_t)E * 4);
    int*   csr     = (int*)  alloc((size_t)E * 4);
    int*   offsets = (int*)  alloc((size_t)n * 4);
    int*   count   = (int*)  alloc((size_t)n * 4);
    float* dinv    = (float*)alloc((size_t)n * 4);
    unsigned int* hs1    = (unsigned int*)alloc((size_t)n * 64 * 2);  // bf16
    unsigned int* h1post = (unsigned int*)alloc((size_t)n * 64 * 2);  // bf16
    unsigned int* hs2    = (unsigned int*)alloc((size_t)n * 32 * 2);  // bf16
    uint4* w1f   = (uint4*)alloc(1024 * 16);
    uint4* w2f   = (uint4*)alloc(256 * 16);
    int*   flag  = (int*)  alloc(4);
    (void)ws_size;

    const int GB = (n + 63) / 64;                    // 1563 MFMA gemm blocks
    const int AG = (n + 3) / 4;
    const int PREP = 2 + (B + THREADS - 1) / THREADS;

    k_prep<<<PREP, THREADS, 0, stream>>>((const unsigned int*)ei, flag, bucket_count, B,
                                         W1, W2, w1f, w2f);
    k_bucket_hist<<<SORT_BLOCKS, THREADS, 0, stream>>>(ei, flag, bucket_count, E, B);
    k_bucket_scan<<<1, 1024, 0, stream>>>(bucket_count, bucket_base, bucket_cursor, B);
    k_bucket_scatter<<<SORT_BLOCKS, THREADS, 0, stream>>>(ei, flag, bucket_cursor, packed, E, B);
    k_fine_sort<<<B, THREADS, 0, stream>>>(packed, bucket_base, bucket_count,
                                           csr, offsets, count, dinv, n, B);
    k_gemm1<<<GB, THREADS, 0, stream>>>(x, w1f, dinv, (unsigned short*)hs1, n);
    k_agg1<<<AG, THREADS, 0, stream>>>(hs1, csr, offsets, count, dinv, b1, h1post, n);
    k_gemm2<<<GB, THREADS, 0, stream>>>((const uint4*)h1post, w2f, dinv, (unsigned short*)hs2, n);
    k_agg2_head<<<AG, THREADS, 0, stream>>>(hs2, csr, offsets, count, dinv, b2, Wfc, bfc, out, n);
}